// Round 1
// baseline (233.469 us; speedup 1.0000x reference)
//
#include <hip/hip_runtime.h>

#define BB    8
#define LQN   2048
#define LKVN  2048
#define DQ    128
#define DVN   128
#define QT    32            // Q rows per block (2 groups of 16)
#define KVW   32            // KV columns owned per wave per iteration
#define KTI   128           // KV per block iteration (4 waves x 32)
#define NT    (LKVN / KTI)  // 16 iterations
#define OSTR  132           // osum row stride (f32, padded)

typedef short short8 __attribute__((ext_vector_type(8)));
typedef float f32x4  __attribute__((ext_vector_type(4)));
typedef int   int4v  __attribute__((ext_vector_type(4)));

__device__ __forceinline__ short f2bf(float f) {
  unsigned u = __builtin_bit_cast(unsigned, f);
  u += 0x7fffu + ((u >> 16) & 1u);   // round-to-nearest-even
  return (short)(u >> 16);
}

__device__ __forceinline__ int packbf(float a, float b) {
  unsigned lo = (unsigned short)f2bf(a);
  unsigned hi = (unsigned short)f2bf(b);
  return (int)(lo | (hi << 16));
}

// Fused preprocessing, one launch:
//   blocks [0,512):    V (B,LKV,DV) fp32 -> Vt (B,DV,LKV) bf16
//   blocks [512,1536): K fp32 -> bf16 flat copy
__global__ __launch_bounds__(256) void pre_kernel(const float* __restrict__ K,
                                                  const float* __restrict__ V,
                                                  short* __restrict__ Kb,
                                                  short* __restrict__ Vt) {
  __shared__ float tile[128][33];
  if (blockIdx.x >= 512) {
    int i = (blockIdx.x - 512) * 256 + threadIdx.x;   // 262144 threads x 8 elems
    size_t off = (size_t)i * 8;
    float4 a = *(const float4*)(K + off);
    float4 c = *(const float4*)(K + off + 4);
    short8 o;
    o[0] = f2bf(a.x); o[1] = f2bf(a.y); o[2] = f2bf(a.z); o[3] = f2bf(a.w);
    o[4] = f2bf(c.x); o[5] = f2bf(c.y); o[6] = f2bf(c.z); o[7] = f2bf(c.w);
    *(short8*)(Kb + off) = o;
    return;
  }
  const int bx  = blockIdx.x;
  const int kv0 = (bx & 15) * 128;
  const int dv0 = ((bx >> 4) & 3) * 32;
  const int b   = bx >> 6;
  const int tid = threadIdx.x;
  const float* src = V + ((size_t)b * LKVN + kv0) * DVN + dv0;
#pragma unroll
  for (int it = 0; it < 4; ++it) {
    int idx = it * 256 + tid;
    int r = idx >> 3, c4 = idx & 7;
    float4 v = *(const float4*)(src + (size_t)r * DVN + c4 * 4);
    tile[r][c4 * 4 + 0] = v.x;
    tile[r][c4 * 4 + 1] = v.y;
    tile[r][c4 * 4 + 2] = v.z;
    tile[r][c4 * 4 + 3] = v.w;
  }
  __syncthreads();
  short* dst = Vt + ((size_t)b * DVN + dv0) * LKVN + kv0;
#pragma unroll
  for (int it = 0; it < 2; ++it) {
    int idx = it * 256 + tid;
    int row = idx >> 4, ch = idx & 15;
    short8 o;
#pragma unroll
    for (int j = 0; j < 8; ++j) o[j] = f2bf(tile[ch * 8 + j][row]);
    *(short8*)(dst + (size_t)row * LKVN + ch * 8) = o;
  }
}

// Barrier-free two-sweep attention.
// Swapped MFMA: S^T = mfma(A=K, B=Q) -> lane holds P^T[kv = 16*t2 + qd*4+r][q = n].
// Wave w owns kv slice [w*32, w*32+32) of each 128-KV iteration; QT=32 q rows/block.
// Phase 1: per-q sums of exp(s). Phase 2: recompute S (same chain), write W as float4,
// intra-wave shfl permutation builds the PV B-fragment (P^T), O^T = mfma(V^T, P^T).
// Final: 4-wave O reduction through LDS (the only barriers in the kernel).
// blockIdx.x & 7 = batch -> XCD-pinned (K/V bf16 ~1 MB stays in one L2).
#define P1_BODY(kc, kn, t)                                                          \
  {                                                                                 \
    if ((t) + 1 < NT) {                                                             \
      _Pragma("unroll")                                                             \
      for (int t2 = 0; t2 < 2; ++t2)                                                \
        _Pragma("unroll")                                                           \
        for (int ks = 0; ks < 4; ++ks)                                              \
          kn[t2 * 4 + ks] =                                                         \
              *(const short8*)(Kw + ((size_t)(((t) + 1) * KTI + t2 * 16)) * DQ + ks * 32); \
    }                                                                               \
    _Pragma("unroll")                                                               \
    for (int g = 0; g < 2; ++g)                                                     \
      _Pragma("unroll")                                                             \
      for (int t2 = 0; t2 < 2; ++t2) {                                              \
        f32x4 acc = {0.f, 0.f, 0.f, 0.f};                                           \
        _Pragma("unroll")                                                           \
        for (int ks = 0; ks < 4; ++ks)                                              \
          acc = __builtin_amdgcn_mfma_f32_16x16x32_bf16(kc[t2 * 4 + ks], qf[g][ks], acc, 0, 0, 0); \
        _Pragma("unroll")                                                           \
        for (int r = 0; r < 4; ++r) l_part[g] += __expf(acc[r] * scale);            \
      }                                                                             \
  }

#define P2_BODY(t)                                                                  \
  {                                                                                 \
    _Pragma("unroll")                                                               \
    for (int t2 = 0; t2 < 2; ++t2)                                                  \
      _Pragma("unroll")                                                             \
      for (int ks = 0; ks < 4; ++ks)                                                \
        kA[t2 * 4 + ks] =                                                           \
            *(const short8*)(Kw + ((size_t)((t) * KTI + t2 * 16)) * DQ + ks * 32);  \
    short8 vf[8];                                                                   \
    _Pragma("unroll")                                                               \
    for (int dvg = 0; dvg < 8; ++dvg)                                               \
      vf[dvg] = *(const short8*)(Vw + (size_t)(dvg * 16) * LKVN + (t) * KTI);       \
    int pk[2][2][2];                                                                \
    _Pragma("unroll")                                                               \
    for (int g = 0; g < 2; ++g)                                                     \
      _Pragma("unroll")                                                             \
      for (int t2 = 0; t2 < 2; ++t2) {                                              \
        f32x4 acc = {0.f, 0.f, 0.f, 0.f};                                           \
        _Pragma("unroll")                                                           \
        for (int ks = 0; ks < 4; ++ks)                                              \
          acc = __builtin_amdgcn_mfma_f32_16x16x32_bf16(kA[t2 * 4 + ks], qf[g][ks], acc, 0, 0, 0); \
        float p0 = __expf(acc[0] * scale) * rinv[g];                                \
        float p1 = __expf(acc[1] * scale) * rinv[g];                                \
        float p2 = __expf(acc[2] * scale) * rinv[g];                                \
        float p3 = __expf(acc[3] * scale) * rinv[g];                                \
        f32x4 st = {p0, p1, p2, p3};                                                \
        *(f32x4*)(Wrow + (size_t)(g * 16) * LKVN + (t) * KTI + t2 * 16) = st;       \
        pk[g][t2][0] = packbf(p0, p1);                                              \
        pk[g][t2][1] = packbf(p2, p3);                                              \
      }                                                                             \
    _Pragma("unroll")                                                               \
    for (int g = 0; g < 2; ++g) {                                                   \
      int a0 = __shfl(pk[g][0][0], srcA, 64);                                       \
      int b0 = __shfl(pk[g][1][0], srcA, 64);                                       \
      int a1 = __shfl(pk[g][0][1], srcA, 64);                                       \
      int b1 = __shfl(pk[g][1][1], srcA, 64);                                       \
      int a2 = __shfl(pk[g][0][0], srcB, 64);                                       \
      int b2 = __shfl(pk[g][1][0], srcB, 64);                                       \
      int a3 = __shfl(pk[g][0][1], srcB, 64);                                       \
      int b3 = __shfl(pk[g][1][1], srcB, 64);                                       \
      int4v bi;                                                                     \
      bi[0] = sel ? b0 : a0;                                                        \
      bi[1] = sel ? b1 : a1;                                                        \
      bi[2] = sel ? b2 : a2;                                                        \
      bi[3] = sel ? b3 : a3;                                                        \
      short8 bfr = __builtin_bit_cast(short8, bi);                                  \
      _Pragma("unroll")                                                             \
      for (int dvg = 0; dvg < 8; ++dvg)                                             \
        oacc[g][dvg] = __builtin_amdgcn_mfma_f32_16x16x32_bf16(vf[dvg], bfr, oacc[g][dvg], 0, 0, 0); \
    }                                                                               \
  }

__global__ __launch_bounds__(256, 2) void attn_kernel(const float* __restrict__ Q,
                                                      const short* __restrict__ Kb,
                                                      const short* __restrict__ Vt,
                                                      float* __restrict__ W,
                                                      float* __restrict__ O) {
  __shared__ __align__(16) float osum[2][QT][OSTR];   // 33.8 KB
  __shared__ float red_l[4][QT];

  const int tid  = threadIdx.x;
  const int w    = tid >> 6;
  const int lane = tid & 63;
  const int n    = lane & 15;
  const int qd   = lane >> 4;
  const int b    = blockIdx.x & 7;           // batch -> XCD
  const int q0   = (blockIdx.x >> 3) * QT;

  const short* Kw = Kb + ((size_t)b * LKVN + w * KVW + n) * DQ + qd * 8;
  const short* Vw = Vt + ((size_t)b * DVN + n) * LKVN + w * KVW + qd * 8;
  float* Wrow = W + ((size_t)b * LQN + q0 + n) * LKVN + w * KVW + qd * 4;

  // Q B-fragments straight from fp32 (per-block one-shot)
  short8 qf[2][4];
#pragma unroll
  for (int g = 0; g < 2; ++g) {
    const float* Qrow = Q + ((size_t)b * LQN + q0 + g * 16 + n) * DQ + qd * 8;
#pragma unroll
    for (int ks = 0; ks < 4; ++ks) {
      float4 f0 = *(const float4*)(Qrow + ks * 32);
      float4 f1 = *(const float4*)(Qrow + ks * 32 + 4);
      short8 o;
      o[0] = f2bf(f0.x); o[1] = f2bf(f0.y); o[2] = f2bf(f0.z); o[3] = f2bf(f0.w);
      o[4] = f2bf(f1.x); o[5] = f2bf(f1.y); o[6] = f2bf(f1.z); o[7] = f2bf(f1.w);
      qf[g][ks] = o;
    }
  }

  const float scale = 0.08838834764831845f;  // 1/sqrt(128)
  float l_part[2] = {0.f, 0.f};

  // ---------------- phase 1: per-q row sums of exp(s), no barriers ----------------
  short8 kA[8], kB[8];
#pragma unroll
  for (int t2 = 0; t2 < 2; ++t2)
#pragma unroll
    for (int ks = 0; ks < 4; ++ks)
      kA[t2 * 4 + ks] = *(const short8*)(Kw + ((size_t)(t2 * 16)) * DQ + ks * 32);

  for (int t = 0; t < NT; t += 2) {
    P1_BODY(kA, kB, t)
    P1_BODY(kB, kA, t + 1)
  }

  // reduce l over qd groups (same q lives in lanes n, n+16, n+32, n+48)
#pragma unroll
  for (int g = 0; g < 2; ++g) {
    l_part[g] += __shfl_xor(l_part[g], 16, 64);
    l_part[g] += __shfl_xor(l_part[g], 32, 64);
  }
  if (lane < 16) {
    red_l[w][lane]      = l_part[0];
    red_l[w][16 + lane] = l_part[1];
  }
  __syncthreads();
  float rinv[2];
#pragma unroll
  for (int g = 0; g < 2; ++g) {
    int qq = g * 16 + n;
    rinv[g] = 1.0f / (red_l[0][qq] + red_l[1][qq] + red_l[2][qq] + red_l[3][qq]);
  }

  // ---------------- phase 2: W write + PV, no barriers ----------------
  const int srcA = n + ((qd & 1) << 5);   // lane of kv block 2*(qd&1)
  const int srcB = srcA + 16;             // lane of kv block 2*(qd&1)+1
  const int sel  = qd >> 1;               // which 16-kv half (t2) this lane consumes

  f32x4 oacc[2][8];
#pragma unroll
  for (int g = 0; g < 2; ++g)
#pragma unroll
    for (int dvg = 0; dvg < 8; ++dvg) oacc[g][dvg] = (f32x4){0.f, 0.f, 0.f, 0.f};

  for (int t = 0; t < NT; ++t) {
    P2_BODY(t)
  }

  // ---------------- cross-wave O reduction (once per block) ----------------
  if (w < 2) {
#pragma unroll
    for (int g = 0; g < 2; ++g)
#pragma unroll
      for (int dvg = 0; dvg < 8; ++dvg)
        *(f32x4*)&osum[w][g * 16 + n][dvg * 16 + qd * 4] = oacc[g][dvg];
  }
  __syncthreads();
  if (w >= 2) {
#pragma unroll
    for (int g = 0; g < 2; ++g)
#pragma unroll
      for (int dvg = 0; dvg < 8; ++dvg) {
        f32x4* p = (f32x4*)&osum[w - 2][g * 16 + n][dvg * 16 + qd * 4];
        *p = *p + oacc[g][dvg];
      }
  }
  __syncthreads();

  float* Ob = O + ((size_t)b * LQN + q0) * DVN;
  const int qq = tid >> 3;
  const int c0 = (tid & 7) * 16;
#pragma unroll
  for (int c = 0; c < 4; ++c) {
    f32x4 s = *(const f32x4*)&osum[0][qq][c0 + c * 4];
    f32x4 s1 = *(const f32x4*)&osum[1][qq][c0 + c * 4];
    s = s + s1;
    *(f32x4*)(Ob + (size_t)qq * DVN + c0 + c * 4) = s;
  }
}

extern "C" void kernel_launch(void* const* d_in, const int* in_sizes, int n_in,
                              void* d_out, int out_size, void* d_ws, size_t ws_size,
                              hipStream_t stream) {
  const float* Q = (const float*)d_in[0];
  const float* K = (const float*)d_in[1];
  const float* V = (const float*)d_in[2];
  float* W = (float*)d_out;                        // (B, LQ, LKV)
  float* O = W + (size_t)BB * LQN * LKVN;          // (B, LQ, DV)
  short* Kb = (short*)d_ws;                        // 4 MB bf16 (B, LKV, D)
  short* Vt = Kb + (size_t)BB * LKVN * DQ;         // 4 MB bf16 (B, DV, LKV)

  pre_kernel<<<1536, 256, 0, stream>>>(K, V, Kb, Vt);
  attn_kernel<<<512, 256, 0, stream>>>(Q, Kb, Vt, W, O);
}